// Round 3
// baseline (57.357 us; speedup 1.0000x reference)
//
#include <hip/hip_runtime.h>
#include <math.h>

#define KPOOL 16
#define SPLIT 8  // threads cooperating on one graph

__device__ __forceinline__ void ce(float& x, float& y) {
  float hi = fmaxf(x, y), lo = fminf(x, y);
  x = hi;
  y = lo;
}

// Batcher odd-even mergesort, 8 inputs, 19 CEs, descending (max at low index).
__device__ __forceinline__ void sort8(float (&v)[8]) {
  ce(v[0], v[1]); ce(v[2], v[3]); ce(v[4], v[5]); ce(v[6], v[7]);
  ce(v[0], v[2]); ce(v[1], v[3]); ce(v[4], v[6]); ce(v[5], v[7]);
  ce(v[1], v[2]); ce(v[5], v[6]);
  ce(v[0], v[4]); ce(v[1], v[5]); ce(v[2], v[6]); ce(v[3], v[7]);
  ce(v[2], v[4]); ce(v[3], v[5]);
  ce(v[1], v[2]); ce(v[3], v[4]); ce(v[5], v[6]);
}

// t: sorted-16 desc. b: sorted-8 desc. Result: t = top-16 of union, sorted.
// C[i]=max(A[i],B'[15-i]) with B' padded by -inf is bitonic -> 4 cleaner stages.
__device__ __forceinline__ void merge8into16(float (&t)[KPOOL], float (&b)[8]) {
#pragma unroll
  for (int i = 8; i < 16; ++i) t[i] = fmaxf(t[i], b[15 - i]);
#pragma unroll
  for (int s = 8; s >= 1; s >>= 1) {
#pragma unroll
    for (int i = 0; i < 16; ++i)
      if ((i & s) == 0) ce(t[i], t[i + s]);
  }
}

// Merge this lane's sorted-16 with partner lane's (lane ^ dist): top-16 of union.
__device__ __forceinline__ void merge_partner(float (&t)[KPOOL], int dist) {
  float c[KPOOL];
#pragma unroll
  for (int i = 0; i < KPOOL; ++i) {
    float o = __shfl_xor(t[KPOOL - 1 - i], dist);
    c[i] = fmaxf(t[i], o);
  }
#pragma unroll
  for (int s = 8; s >= 1; s >>= 1) {
#pragma unroll
    for (int i = 0; i < KPOOL; ++i)
      if ((i & s) == 0) ce(c[i], c[i + s]);
  }
#pragma unroll
  for (int i = 0; i < KPOOL; ++i) t[i] = c[i];
}

__device__ __forceinline__ int lower_bound_scalar(const int* __restrict__ a,
                                                  int nn, int key) {
  int lo = 0, hi = nn;
  while (lo < hi) {
    int mid = (lo + hi) >> 1;
    if (a[mid] < key) lo = mid + 1;
    else hi = mid;
  }
  return lo;
}

// starts[g] = first index with emap[i] >= g, g in [0,n]. Thread 0 also
// precomputes softmax(W) into wn_out (grid-uniform).
__global__ __launch_bounds__(256)
void boundary_kernel(const int* __restrict__ emap, int total, int n,
                     int* __restrict__ starts, float* __restrict__ wn_out,
                     const float* __restrict__ W) {
  int g = blockIdx.x * 256 + threadIdx.x;
  if (g == 0) {
    float w[KPOOL], m = -INFINITY, s = 0.0f;
#pragma unroll
    for (int k = 0; k < KPOOL; ++k) { w[k] = W[k]; m = fmaxf(m, w[k]); }
#pragma unroll
    for (int k = 0; k < KPOOL; ++k) { w[k] = expf(w[k] - m); s += w[k]; }
#pragma unroll
    for (int k = 0; k < KPOOL; ++k) wn_out[k] = w[k] / s;
  }
  if (g > n) return;
  starts[g] = lower_bound_scalar(emap, total, g);
}

__global__ __launch_bounds__(256, 8)
void sortpool_main(const float* __restrict__ Y, const float* __restrict__ W,
                   const int* __restrict__ starts, const float* __restrict__ Wn,
                   const int* __restrict__ emap,
                   float* __restrict__ out, int total, int n) {
  const int tid = blockIdx.x * 256 + threadIdx.x;
  const int g = tid >> 3;  // graph id; 8 consecutive lanes share a graph
  const int q = tid & 7;   // chunk id
  if (g >= n) return;

  int s0, s1;
  if (starts) {
    s0 = starts[g];
    s1 = starts[g + 1];
  } else {  // fallback if ws too small
    s0 = lower_bound_scalar(emap, total, g);
    s1 = lower_bound_scalar(emap, total, g + 1);
  }
  const int len = s1 - s0;
  const int a = s0 + ((len * q) >> 3);
  const int b = s0 + ((len * (q + 1)) >> 3);

  float t[KPOOL];
#pragma unroll
  for (int i = 0; i < KPOOL; ++i) t[i] = -INFINITY;

  // head batch: aligned base, fully guarded loads (also handles tiny chunks)
  const int abase = a & ~7;
  {
    float v[8];
#pragma unroll
    for (int j = 0; j < 8; ++j) {
      int idx = abase + j;
      v[j] = (idx >= a && idx < b) ? Y[idx] : -INFINITY;
    }
    sort8(v);
    merge8into16(t, v);
  }
  // interior: branchless vectorized batches of 8 (32B-aligned)
  int base = abase + 8;
#pragma unroll 1
  for (; base + 8 <= b; base += 8) {
    const float4 x0 = *reinterpret_cast<const float4*>(Y + base);
    const float4 x1 = *reinterpret_cast<const float4*>(Y + base + 4);
    float v[8] = {x0.x, x0.y, x0.z, x0.w, x1.x, x1.y, x1.z, x1.w};
    sort8(v);
    merge8into16(t, v);
  }
  // tail batch (guarded above by idx<b; idx>=a guaranteed since base>=abase+8>a-8+8)
  if (base < b) {
    float v[8];
#pragma unroll
    for (int j = 0; j < 8; ++j) {
      int idx = base + j;
      v[j] = (idx < b) ? Y[idx] : -INFINITY;
    }
    sort8(v);
    merge8into16(t, v);
  }

  // combine the 8 chunks' sorted top-16 lists (butterfly; all lanes end equal)
  merge_partner(t, 1);
  merge_partner(t, 2);
  merge_partner(t, 4);

  // weighted sum with precomputed softmax(W); -inf slots (exhausted) -> 0
  float res = 0.0f;
  if (Wn) {
#pragma unroll
    for (int k = 0; k < KPOOL; ++k) {
      float tv = t[k];
      res += (tv > -INFINITY) ? tv * Wn[k] : 0.0f;
    }
  } else {  // fallback: inline softmax
    float wv[KPOOL], m = -INFINITY, s = 0.0f;
#pragma unroll
    for (int k = 0; k < KPOOL; ++k) { wv[k] = W[k]; m = fmaxf(m, wv[k]); }
#pragma unroll
    for (int k = 0; k < KPOOL; ++k) { wv[k] = expf(wv[k] - m); s += wv[k]; }
    const float inv = 1.0f / s;
#pragma unroll
    for (int k = 0; k < KPOOL; ++k) {
      float tv = t[k];
      res += (tv > -INFINITY) ? tv * (wv[k] * inv) : 0.0f;
    }
  }

  if (q == 0) out[g] = res;
}

extern "C" void kernel_launch(void* const* d_in, const int* in_sizes, int n_in,
                              void* d_out, int out_size, void* d_ws, size_t ws_size,
                              hipStream_t stream) {
  const float* Y = (const float*)d_in[0];   // [TOTAL]
  const float* W = (const float*)d_in[1];   // [16]
  const int* emap = (const int*)d_in[2];    // [TOTAL], sorted
  const int total = in_sizes[0];
  const int n = in_sizes[3];                // len(v_count)
  float* out = (float*)d_out;               // [N] float32

  int* starts = (int*)d_ws;
  float* wn_buf = (float*)((char*)d_ws + (size_t)(n + 1) * sizeof(int));
  const bool use_ws =
      (ws_size >= (size_t)(n + 1) * sizeof(int) + KPOOL * sizeof(float));

  if (use_ws) {
    int nb = (n + 1 + 255) / 256;
    boundary_kernel<<<nb, 256, 0, stream>>>(emap, total, n, starts, wn_buf, W);
  }

  long long threads = (long long)n * SPLIT;
  int blocks = (int)((threads + 255) / 256);
  sortpool_main<<<blocks, 256, 0, stream>>>(Y, W, use_ws ? starts : nullptr,
                                            use_ws ? wn_buf : nullptr,
                                            emap, out, total, n);
}

// Round 4
// 36.262 us; speedup vs baseline: 1.5817x; 1.5817x over previous
//
#include <hip/hip_runtime.h>
#include <math.h>

#define KPOOL 16
#define SPLIT 8  // threads cooperating on one graph

__device__ __forceinline__ void ce(float& x, float& y) {
  float hi = fmaxf(x, y), lo = fminf(x, y);
  x = hi;
  y = lo;
}

// Batcher odd-even mergesort, 8 inputs, 19 CEs, descending (max at low index).
__device__ __forceinline__ void sort8(float (&v)[8]) {
  ce(v[0], v[1]); ce(v[2], v[3]); ce(v[4], v[5]); ce(v[6], v[7]);
  ce(v[0], v[2]); ce(v[1], v[3]); ce(v[4], v[6]); ce(v[5], v[7]);
  ce(v[1], v[2]); ce(v[5], v[6]);
  ce(v[0], v[4]); ce(v[1], v[5]); ce(v[2], v[6]); ce(v[3], v[7]);
  ce(v[2], v[4]); ce(v[3], v[5]);
  ce(v[1], v[2]); ce(v[3], v[4]); ce(v[5], v[6]);
}

// t: sorted-16 desc. b: sorted-8 desc. Result: t = top-16 of union, sorted.
// C[i]=max(A[i],B'[15-i]) with B' -inf-padded is bitonic -> 4 cleaner stages.
__device__ __forceinline__ void merge8into16(float (&t)[KPOOL], const float (&b)[8]) {
#pragma unroll
  for (int i = 8; i < 16; ++i) t[i] = fmaxf(t[i], b[15 - i]);
#pragma unroll
  for (int s = 8; s >= 1; s >>= 1) {
#pragma unroll
    for (int i = 0; i < 16; ++i)
      if ((i & s) == 0) ce(t[i], t[i + s]);
  }
}

// Merge this lane's sorted-16 with partner lane's (lane ^ dist): top-16 of union.
__device__ __forceinline__ void merge_partner(float (&t)[KPOOL], int dist) {
  float c[KPOOL];
#pragma unroll
  for (int i = 0; i < KPOOL; ++i) {
    float o = __shfl_xor(t[KPOOL - 1 - i], dist);
    c[i] = fmaxf(t[i], o);
  }
#pragma unroll
  for (int s = 8; s >= 1; s >>= 1) {
#pragma unroll
    for (int i = 0; i < KPOOL; ++i)
      if ((i & s) == 0) ce(c[i], c[i + s]);
  }
#pragma unroll
  for (int i = 0; i < KPOOL; ++i) t[i] = c[i];
}

__device__ __forceinline__ int lower_bound_range(const int* __restrict__ a,
                                                 int lo, int hi, int key) {
  while (lo < hi) {
    int mid = (lo + hi) >> 1;
    if (a[mid] < key) lo = mid + 1;
    else hi = mid;
  }
  return lo;
}

// starts[g] = first index with emap[i] >= g, g in [0,n]. Windowed search around
// expected position (boundaries are Binomial, sigma<=2048); exact verify +
// full-range fallback. Thread 0 precomputes softmax(W).
__global__ __launch_bounds__(256)
void boundary_kernel(const int* __restrict__ emap, int total, int n,
                     int* __restrict__ starts, float* __restrict__ wn_out,
                     const float* __restrict__ W) {
  int g = blockIdx.x * 256 + threadIdx.x;
  if (g == 0) {
    float w[KPOOL], m = -INFINITY, s = 0.0f;
#pragma unroll
    for (int k = 0; k < KPOOL; ++k) { w[k] = W[k]; m = fmaxf(m, w[k]); }
#pragma unroll
    for (int k = 0; k < KPOOL; ++k) { w[k] = expf(w[k] - m); s += w[k]; }
#pragma unroll
    for (int k = 0; k < KPOOL; ++k) wn_out[k] = w[k] / s;
  }
  if (g > n) return;
  long long E = (long long)g * total / n;
  int wlo = (int)(E - 8192 > 0 ? E - 8192 : 0);
  int whi = (int)(E + 8192 < total ? E + 8192 : total);
  bool ok = ((wlo == 0) || (emap[wlo - 1] < g)) &&
            ((whi == total) || (emap[whi] >= g));
  if (!ok) { wlo = 0; whi = total; }
  starts[g] = lower_bound_range(emap, wlo, whi, g);
}

__global__ __launch_bounds__(256, 4)
void sortpool_main(const float* __restrict__ Y, const float* __restrict__ W,
                   const int* __restrict__ starts, const float* __restrict__ Wn,
                   const int* __restrict__ emap,
                   float* __restrict__ out, int total, int n) {
  const int tid = blockIdx.x * 256 + threadIdx.x;
  const int g = tid >> 3;  // graph id; 8 consecutive lanes share a graph
  const int q = tid & 7;   // stride id
  if (g >= n) return;

  int s0, s1;
  if (starts) {
    s0 = starts[g];
    s1 = starts[g + 1];
  } else {  // fallback if ws too small
    s0 = lower_bound_range(emap, 0, total, g);
    s1 = lower_bound_range(emap, 0, total, g + 1);
  }
  const unsigned len = (unsigned)(s1 - s0);

  // Segment owns absolute 8-element blocks [B0, B1); every load is an aligned
  // 32B pair of float4s; partial coverage handled by one range compare/elem.
  const int B0 = s0 >> 3;
  const int B1 = (s1 + 7) >> 3;

  float t[KPOOL];
#pragma unroll
  for (int i = 0; i < KPOOL; ++i) t[i] = -INFINITY;

  int b = B0 + q;
  float4 n0, n1;
  if (b < B1) {
    const float4* p = reinterpret_cast<const float4*>(Y + (b << 3));
    n0 = p[0];
    n1 = p[1];
  }
#pragma unroll 1
  while (b < B1) {
    const float4 c0 = n0, c1 = n1;
    const int base = b << 3;
    const int bn = b + SPLIT;
    if (bn < B1) {  // prefetch next batch before consuming current
      const float4* p = reinterpret_cast<const float4*>(Y + (bn << 3));
      n0 = p[0];
      n1 = p[1];
    }
    float v[8] = {c0.x, c0.y, c0.z, c0.w, c1.x, c1.y, c1.z, c1.w};
#pragma unroll
    for (int j = 0; j < 8; ++j) {
      // valid iff s0 <= base+j < s1, as one unsigned compare
      if ((unsigned)(base + j - s0) >= len) v[j] = -INFINITY;
    }
    sort8(v);
    merge8into16(t, v);
    b = bn;
  }

  // combine the 8 strides' sorted top-16 lists (butterfly; all lanes equal)
  merge_partner(t, 1);
  merge_partner(t, 2);
  merge_partner(t, 4);

  // weighted sum with precomputed softmax(W); -inf slots (exhausted) -> 0
  float res = 0.0f;
  if (Wn) {
#pragma unroll
    for (int k = 0; k < KPOOL; ++k) {
      float tv = t[k];
      res += (tv > -INFINITY) ? tv * Wn[k] : 0.0f;
    }
  } else {  // fallback: inline softmax
    float wv[KPOOL], m = -INFINITY, s = 0.0f;
#pragma unroll
    for (int k = 0; k < KPOOL; ++k) { wv[k] = W[k]; m = fmaxf(m, wv[k]); }
#pragma unroll
    for (int k = 0; k < KPOOL; ++k) { wv[k] = expf(wv[k] - m); s += wv[k]; }
    const float inv = 1.0f / s;
#pragma unroll
    for (int k = 0; k < KPOOL; ++k) {
      float tv = t[k];
      res += (tv > -INFINITY) ? tv * (wv[k] * inv) : 0.0f;
    }
  }

  if (q == 0) out[g] = res;
}

extern "C" void kernel_launch(void* const* d_in, const int* in_sizes, int n_in,
                              void* d_out, int out_size, void* d_ws, size_t ws_size,
                              hipStream_t stream) {
  const float* Y = (const float*)d_in[0];   // [TOTAL]
  const float* W = (const float*)d_in[1];   // [16]
  const int* emap = (const int*)d_in[2];    // [TOTAL], sorted
  const int total = in_sizes[0];
  const int n = in_sizes[3];                // len(v_count)
  float* out = (float*)d_out;               // [N] float32

  int* starts = (int*)d_ws;
  float* wn_buf = (float*)((char*)d_ws + (size_t)(n + 1) * sizeof(int));
  const bool use_ws =
      (ws_size >= (size_t)(n + 1) * sizeof(int) + KPOOL * sizeof(float));

  if (use_ws) {
    int nb = (n + 1 + 255) / 256;
    boundary_kernel<<<nb, 256, 0, stream>>>(emap, total, n, starts, wn_buf, W);
  }

  long long threads = (long long)n * SPLIT;
  int blocks = (int)((threads + 255) / 256);
  sortpool_main<<<blocks, 256, 0, stream>>>(Y, W, use_ws ? starts : nullptr,
                                            use_ws ? wn_buf : nullptr,
                                            emap, out, total, n);
}